// Round 1
// baseline (451.781 us; speedup 1.0000x reference)
//
#include <hip/hip_runtime.h>
#include <hip/hip_bf16.h>

// CrossAttentionFusion: B=4, C=Cs=256, CI=128, H=W=64 -> N=M=4096
// Strategy:
//  - proj_split: q^T,k^T [b][n][128] as hi/lo bf16 split (fp32 accuracy for logits);
//    log2e folded into q so softmax uses exp2 (v_exp_f32) directly.
//  - proj_v: v [b][o][m] plain bf16 (error enters scaled by gamma ~0.1).
//  - attn: flash-style online softmax, 32 Q-rows/block, 128 keys/iter,
//    mfma_f32_32x32x16_bf16; S = qh*kh + ql*kh + qh*kl (3-MFMA split).
//    P goes C/D-layout -> LDS -> A-layout (guide Sec 5 flash pattern).
//    Epilogue: LDS transpose, coalesced fp32 write of gamma*O/l + x_main.

typedef __bf16  bf16x8  __attribute__((ext_vector_type(8)));
typedef float   f32x16  __attribute__((ext_vector_type(16)));

#define LOG2E 1.4426950408889634f

// ---------------------------------------------------------------------------
// Projection (split): out^T[b][n][OTOT=128] = (W X + b) * scale, hi/lo bf16.
// lanes -> o (coalesced [n][o] writes), waves -> n.
// ---------------------------------------------------------------------------
__global__ __launch_bounds__(256) void proj_split(
    const float* __restrict__ X, const float* __restrict__ W,
    const float* __restrict__ bias,
    __hip_bfloat16* __restrict__ oh, __hip_bfloat16* __restrict__ ol,
    float scale)
{
  const int b  = blockIdx.x >> 6;
  const int n0 = (blockIdx.x & 63) * 64;
  const int tid = threadIdx.x;
  const int o  = tid & 63;      // lane -> output channel (and o+64)
  const int wv = tid >> 6;      // wave -> n-subtile of 16

  __shared__ float lx[16][64];    // [cc][n] tile of X
  __shared__ float lw[128][17];   // [o][cc], pad 17 -> conflict-free

  float acc[2][16];
#pragma unroll
  for (int g = 0; g < 2; g++)
#pragma unroll
    for (int k = 0; k < 16; k++) acc[g][k] = 0.f;

  const size_t xb = (size_t)b * 256 * 4096;
  for (int c0 = 0; c0 < 256; c0 += 16) {
#pragma unroll
    for (int i = 0; i < 4; i++) {           // 1024 floats, coalesced
      int idx = i * 256 + tid; int cc = idx >> 6, nn = idx & 63;
      lx[cc][nn] = X[xb + (size_t)(c0 + cc) * 4096 + n0 + nn];
    }
#pragma unroll
    for (int i = 0; i < 8; i++) {           // 2048 floats
      int idx = i * 256 + tid; int oo = idx >> 4, cc = idx & 15;
      lw[oo][cc] = W[oo * 256 + c0 + cc];
    }
    __syncthreads();
#pragma unroll
    for (int cc = 0; cc < 16; cc++) {
      float w0 = lw[o][cc], w1 = lw[o + 64][cc];   // stride-17: conflict-free
      const float4* xp = (const float4*)&lx[cc][wv * 16];  // wave-broadcast b128
#pragma unroll
      for (int k4 = 0; k4 < 4; k4++) {
        float4 xv = xp[k4];
        float xs[4] = {xv.x, xv.y, xv.z, xv.w};
#pragma unroll
        for (int k = 0; k < 4; k++) {
          acc[0][k4 * 4 + k] += w0 * xs[k];
          acc[1][k4 * 4 + k] += w1 * xs[k];
        }
      }
    }
    __syncthreads();
  }

  float bb[2] = {bias[o], bias[o + 64]};
#pragma unroll
  for (int g = 0; g < 2; g++)
#pragma unroll
    for (int k = 0; k < 16; k++) {
      float val = (acc[g][k] + bb[g]) * scale;
      __hip_bfloat16 hi = __float2bfloat16(val);
      __hip_bfloat16 lo = __float2bfloat16(val - __bfloat162float(hi));
      size_t idx = ((size_t)(b * 4096 + n0 + wv * 16 + k)) * 128 + g * 64 + o;
      oh[idx] = hi; ol[idx] = lo;
    }
}

// ---------------------------------------------------------------------------
// Projection (v): v[b][o=256][m] = Wv z + bv, plain bf16.
// lanes -> o for compute; LDS transpose for coalesced [o][m] writes.
// ---------------------------------------------------------------------------
struct ProjVSmem {
  union {
    struct { float lx[16][64]; float lw[256][17]; } a;
    __hip_bfloat16 t[256][66];   // transpose staging, pad 66 -> conflict-free
  };
};

__global__ __launch_bounds__(256) void proj_v(
    const float* __restrict__ X, const float* __restrict__ W,
    const float* __restrict__ bias, __hip_bfloat16* __restrict__ outv)
{
  __shared__ ProjVSmem sm;
  const int b  = blockIdx.x >> 6;
  const int n0 = (blockIdx.x & 63) * 64;
  const int tid = threadIdx.x;
  const int o  = tid & 63;
  const int wv = tid >> 6;

  float acc[4][16];
#pragma unroll
  for (int g = 0; g < 4; g++)
#pragma unroll
    for (int k = 0; k < 16; k++) acc[g][k] = 0.f;

  const size_t xb = (size_t)b * 256 * 4096;
  for (int c0 = 0; c0 < 256; c0 += 16) {
#pragma unroll
    for (int i = 0; i < 4; i++) {
      int idx = i * 256 + tid; int cc = idx >> 6, nn = idx & 63;
      sm.a.lx[cc][nn] = X[xb + (size_t)(c0 + cc) * 4096 + n0 + nn];
    }
#pragma unroll
    for (int i = 0; i < 16; i++) {
      int idx = i * 256 + tid; int oo = idx >> 4, cc = idx & 15;
      sm.a.lw[oo][cc] = W[oo * 256 + c0 + cc];
    }
    __syncthreads();
#pragma unroll
    for (int cc = 0; cc < 16; cc++) {
      float w[4] = {sm.a.lw[o][cc], sm.a.lw[o + 64][cc],
                    sm.a.lw[o + 128][cc], sm.a.lw[o + 192][cc]};
      const float4* xp = (const float4*)&sm.a.lx[cc][wv * 16];
#pragma unroll
      for (int k4 = 0; k4 < 4; k4++) {
        float4 xv = xp[k4];
        float xs[4] = {xv.x, xv.y, xv.z, xv.w};
#pragma unroll
        for (int k = 0; k < 4; k++)
#pragma unroll
          for (int g = 0; g < 4; g++)
            acc[g][k4 * 4 + k] += w[g] * xs[k];
      }
    }
    __syncthreads();
  }

  // bias + cast + transpose-stage (aliases lx/lw: all compute done, synced above)
#pragma unroll
  for (int g = 0; g < 4; g++) {
    float bb = bias[g * 64 + o];
#pragma unroll
    for (int k = 0; k < 16; k++)
      sm.t[g * 64 + o][wv * 16 + k] = __float2bfloat16(acc[g][k] + bb);
  }
  __syncthreads();
  const int n = tid & 63;
  const int orow = tid >> 6;
#pragma unroll
  for (int j = 0; j < 64; j++) {
    int oo = orow * 64 + j;
    outv[((size_t)(b * 256 + oo)) * 4096 + n0 + n] = sm.t[oo][n];
  }
}

// ---------------------------------------------------------------------------
// Flash attention. Block: batch b, 32 query rows. 4 waves, 128 keys/iter.
// ---------------------------------------------------------------------------
struct alignas(16) AttnSmem {
  union {
    struct {
      __hip_bfloat16 P[32][136];  // [n][m], stride 136 (272B = 17*16: b128-aligned)
      float smax[4][32];
      float ssum[4][32];
      float m[32];
      float alpha[32];
    } s;
    float ostage[256][33];        // epilogue transpose, pad 33 -> conflict-free
  };
  float l[32];                    // running denominator (outside union)
};

__global__ __launch_bounds__(256) void attn_kernel(
    const __hip_bfloat16* __restrict__ qh, const __hip_bfloat16* __restrict__ ql,
    const __hip_bfloat16* __restrict__ kh, const __hip_bfloat16* __restrict__ kl,
    const __hip_bfloat16* __restrict__ vv,
    const float* __restrict__ x_main, const float* __restrict__ gammap,
    float* __restrict__ out)
{
  __shared__ AttnSmem sm;
  const int i  = blockIdx.x;
  // XCD-stable mapping: blockIdx%8 -> XCD (measured m09); pin each XCD pair to
  // one batch so K+V (~4MB/batch) stays L2-resident.
  const int b  = (i & 7) >> 1;
  const int nt = ((i >> 3) << 1) | (i & 1);
  const int n0 = nt * 32;
  const int tid = threadIdx.x;
  const int wv = tid >> 6, lane = tid & 63, l32 = lane & 31, half = lane >> 5;

  if (tid < 32) { sm.s.m[tid] = -INFINITY; sm.l[tid] = 0.f; }

  // Q fragments: A[m=l32][k=half*8+j], 8 k-steps, hi+lo (64 VGPRs)
  bf16x8 qfh[8], qfl[8];
  {
    const __hip_bfloat16* q1 = qh + ((size_t)(b * 4096 + n0 + l32)) * 128 + half * 8;
    const __hip_bfloat16* q2 = ql + ((size_t)(b * 4096 + n0 + l32)) * 128 + half * 8;
#pragma unroll
    for (int cs = 0; cs < 8; cs++) {
      qfh[cs] = *(const bf16x8*)(q1 + cs * 16);
      qfl[cs] = *(const bf16x8*)(q2 + cs * 16);
    }
  }

  f32x16 Oacc[2];
#pragma unroll
  for (int t = 0; t < 2; t++)
#pragma unroll
    for (int r = 0; r < 16; r++) Oacc[t][r] = 0.f;

  const int o0 = wv * 64;   // this wave's 64 output channels in PV

#pragma unroll 1
  for (int it = 0; it < 32; it++) {
    const int mb = it * 128 + wv * 32;   // wave's 32-key chunk

    // ---- S = Q^T K (hi/lo split: 3 MFMAs per k-step) ----
    f32x16 S;
#pragma unroll
    for (int r = 0; r < 16; r++) S[r] = 0.f;
    {
      const __hip_bfloat16* k1 = kh + ((size_t)(b * 4096 + mb + l32)) * 128 + half * 8;
      const __hip_bfloat16* k2 = kl + ((size_t)(b * 4096 + mb + l32)) * 128 + half * 8;
#pragma unroll
      for (int cs = 0; cs < 8; cs++) {
        bf16x8 kfh = *(const bf16x8*)(k1 + cs * 16);
        bf16x8 kfl = *(const bf16x8*)(k2 + cs * 16);
        S = __builtin_amdgcn_mfma_f32_32x32x16_bf16(qfh[cs], kfh, S, 0, 0, 0);
        S = __builtin_amdgcn_mfma_f32_32x32x16_bf16(qfl[cs], kfh, S, 0, 0, 0);
        S = __builtin_amdgcn_mfma_f32_32x32x16_bf16(qfh[cs], kfl, S, 0, 0, 0);
      }
    }

    // ---- per-wave row max (C/D layout: col=l32, row=(r&3)+8*(r>>2)+4*half) ----
    float mx[16];
#pragma unroll
    for (int r = 0; r < 16; r++) {
      float v = S[r];
#pragma unroll
      for (int off = 1; off < 32; off <<= 1) v = fmaxf(v, __shfl_xor(v, off));
      mx[r] = v;
    }
    if (l32 == 0) {
#pragma unroll
      for (int r = 0; r < 16; r++)
        sm.s.smax[wv][(r & 3) + 8 * (r >> 2) + 4 * half] = mx[r];
    }
    __syncthreads();                                   // sync1

    if (tid < 32) {
      float cm = fmaxf(fmaxf(sm.s.smax[0][tid], sm.s.smax[1][tid]),
                       fmaxf(sm.s.smax[2][tid], sm.s.smax[3][tid]));
      float mold = sm.s.m[tid];
      float mnew = fmaxf(mold, cm);
      sm.s.alpha[tid] = exp2f(mold - mnew);
      sm.s.m[tid] = mnew;
    }
    __syncthreads();                                   // sync2

    // ---- P = exp2(S - m), row sums, O rescale ----
    float ps[16];
#pragma unroll
    for (int r = 0; r < 16; r++) {
      int row = (r & 3) + 8 * (r >> 2) + 4 * half;
      float p = exp2f(S[r] - sm.s.m[row]);
      sm.s.P[row][wv * 32 + l32] = __float2bfloat16(p);
      float sv = p;
#pragma unroll
      for (int off = 1; off < 32; off <<= 1) sv += __shfl_xor(sv, off);
      ps[r] = sv;
      float a = sm.s.alpha[row];
      Oacc[0][r] *= a;
      Oacc[1][r] *= a;
    }
    if (l32 == 0) {
#pragma unroll
      for (int r = 0; r < 16; r++)
        sm.s.ssum[wv][(r & 3) + 8 * (r >> 2) + 4 * half] = ps[r];
    }
    __syncthreads();                                   // sync3

    if (tid < 32) {
      sm.l[tid] = sm.s.alpha[tid] * sm.l[tid]
                + sm.s.ssum[0][tid] + sm.s.ssum[1][tid]
                + sm.s.ssum[2][tid] + sm.s.ssum[3][tid];
    }

    // ---- O += P V^T : A=P from LDS (A-layout), B=v[o][m] 16B loads ----
#pragma unroll
    for (int ch = 0; ch < 4; ch++) {
#pragma unroll
      for (int ks = 0; ks < 2; ks++) {
        bf16x8 pf = *(const bf16x8*)&sm.s.P[l32][ch * 32 + ks * 16 + half * 8];
#pragma unroll
        for (int ot = 0; ot < 2; ot++) {
          const __hip_bfloat16* vb = vv
              + ((size_t)(b * 256 + o0 + ot * 32 + l32)) * 4096
              + it * 128 + ch * 32 + ks * 16 + half * 8;
          bf16x8 vf = *(const bf16x8*)vb;
          Oacc[ot] = __builtin_amdgcn_mfma_f32_32x32x16_bf16(pf, vf, Oacc[ot], 0, 0, 0);
        }
      }
    }
    // next iter's sync1 protects P/smax reuse; no barrier needed here
  }

  // ---- epilogue: transpose O via LDS, write gamma*O/l + x_main coalesced ----
  __syncthreads();
#pragma unroll
  for (int ot = 0; ot < 2; ot++)
#pragma unroll
    for (int r = 0; r < 16; r++) {
      int row = (r & 3) + 8 * (r >> 2) + 4 * half;
      sm.ostage[o0 + ot * 32 + l32][row] = Oacc[ot][r];
    }
  __syncthreads();
  const float gmm = gammap[0];
  const int nr = tid & 31;
  const int og = tid >> 5;
  const float rinv = 1.0f / sm.l[nr];
#pragma unroll
  for (int j = 0; j < 32; j++) {
    int oo = og * 32 + j;
    size_t g = ((size_t)(b * 256 + oo)) * 4096 + n0 + nr;
    out[g] = gmm * sm.ostage[oo][nr] * rinv + x_main[g];
  }
}

// ---------------------------------------------------------------------------
extern "C" void kernel_launch(void* const* d_in, const int* in_sizes, int n_in,
                              void* d_out, int out_size, void* d_ws, size_t ws_size,
                              hipStream_t stream) {
  (void)in_sizes; (void)n_in; (void)out_size; (void)ws_size;
  const float* x  = (const float*)d_in[0];
  const float* z  = (const float*)d_in[1];
  const float* Wq = (const float*)d_in[2];
  const float* bq = (const float*)d_in[3];
  const float* Wk = (const float*)d_in[4];
  const float* bk = (const float*)d_in[5];
  const float* Wv = (const float*)d_in[6];
  const float* bv = (const float*)d_in[7];
  const float* gm = (const float*)d_in[8];
  float* out = (float*)d_out;

  char* ws = (char*)d_ws;
  const size_t QSZ = (size_t)4 * 4096 * 128 * sizeof(__hip_bfloat16);  // 4 MiB
  __hip_bfloat16* qhp = (__hip_bfloat16*)(ws);
  __hip_bfloat16* qlp = (__hip_bfloat16*)(ws + QSZ);
  __hip_bfloat16* khp = (__hip_bfloat16*)(ws + 2 * QSZ);
  __hip_bfloat16* klp = (__hip_bfloat16*)(ws + 3 * QSZ);
  __hip_bfloat16* vp  = (__hip_bfloat16*)(ws + 4 * QSZ);               // 8 MiB

  proj_split<<<256, 256, 0, stream>>>(x, Wq, bq, qhp, qlp, LOG2E);  // q scaled by log2e
  proj_split<<<256, 256, 0, stream>>>(z, Wk, bk, khp, klp, 1.0f);
  proj_v    <<<256, 256, 0, stream>>>(z, Wv, bv, vp);
  attn_kernel<<<512, 256, 0, stream>>>(qhp, qlp, khp, klp, vp, x, gm, out);
}

// Round 2
// 392.216 us; speedup vs baseline: 1.1519x; 1.1519x over previous
//
#include <hip/hip_runtime.h>
#include <hip/hip_bf16.h>

// CrossAttentionFusion: B=4, C=Cs=256, CI=128, H=W=64 -> N=M=4096
// R2: barrier-free flash attention.
//  - proj_fused: one kernel, 768 blocks (q: 0-255, k: 256-511, v: 512-767),
//    fp32 VALU math (accuracy), bf16 outputs. log2e folded into q.
//  - attn: S^T = K*Q (operand swap) puts query on lanes, keys on regs ->
//    softmax reductions are in-register (15 fmax + 1 shfl) instead of
//    5-step shuffle trees. Fixed anchor m0 (max of first 128 keys, one
//    LDS exchange) -> no online rescale of the 128-reg O accumulator.
//    P C/D->A-layout via 8 packed shfl_xor(32) + cndmask, no LDS.
//    Per-wave private 1024-key range: zero barriers in the main loop.
//    O merged across waves at the end via 4-phase rotated LDS accumulate.

typedef __bf16  bf16x8  __attribute__((ext_vector_type(8)));
typedef float   f32x16  __attribute__((ext_vector_type(16)));

#define LOG2E 1.4426950408889634f

// ---------------------------------------------------------------------------
// Fused projections.
// ---------------------------------------------------------------------------
union ProjSmem {
  struct { float lx[16][64]; float lw[128][17]; } qk;
  struct { float lx[16][64]; float lw[256][17]; } v;
  __hip_bfloat16 t[256][66];   // transpose staging (v), pad 66 -> conflict-free
};

// out[b][n][128] = bf16((W X + b) * scale), lanes -> o, waves -> n.
__device__ inline void proj_qk_body(
    const float* __restrict__ X, const float* __restrict__ W,
    const float* __restrict__ bias, __hip_bfloat16* __restrict__ oq,
    float scale, int idx, ProjSmem& sm)
{
  const int b  = idx >> 6;
  const int n0 = (idx & 63) * 64;
  const int tid = threadIdx.x;
  const int o  = tid & 63;
  const int wv = tid >> 6;

  float acc[2][16];
#pragma unroll
  for (int g = 0; g < 2; g++)
#pragma unroll
    for (int k = 0; k < 16; k++) acc[g][k] = 0.f;

  const size_t xb = (size_t)b * 256 * 4096;
  for (int c0 = 0; c0 < 256; c0 += 16) {
#pragma unroll
    for (int i = 0; i < 4; i++) {
      int ii = i * 256 + tid; int cc = ii >> 6, nn = ii & 63;
      sm.qk.lx[cc][nn] = X[xb + (size_t)(c0 + cc) * 4096 + n0 + nn];
    }
#pragma unroll
    for (int i = 0; i < 8; i++) {
      int ii = i * 256 + tid; int oo = ii >> 4, cc = ii & 15;
      sm.qk.lw[oo][cc] = W[oo * 256 + c0 + cc];
    }
    __syncthreads();
#pragma unroll
    for (int cc = 0; cc < 16; cc++) {
      float w0 = sm.qk.lw[o][cc], w1 = sm.qk.lw[o + 64][cc];
      const float4* xp = (const float4*)&sm.qk.lx[cc][wv * 16];
#pragma unroll
      for (int k4 = 0; k4 < 4; k4++) {
        float4 xv = xp[k4];
        float xs[4] = {xv.x, xv.y, xv.z, xv.w};
#pragma unroll
        for (int k = 0; k < 4; k++) {
          acc[0][k4 * 4 + k] += w0 * xs[k];
          acc[1][k4 * 4 + k] += w1 * xs[k];
        }
      }
    }
    __syncthreads();
  }

  float bb[2] = {bias[o], bias[o + 64]};
#pragma unroll
  for (int g = 0; g < 2; g++)
#pragma unroll
    for (int k = 0; k < 16; k++) {
      float val = (acc[g][k] + bb[g]) * scale;
      size_t ix = ((size_t)(b * 4096 + n0 + wv * 16 + k)) * 128 + g * 64 + o;
      oq[ix] = __float2bfloat16(val);
    }
}

// v[b][o=256][m] = bf16(Wv z + bv): compute then LDS transpose for [o][m] writes.
__device__ inline void proj_v_body(
    const float* __restrict__ X, const float* __restrict__ W,
    const float* __restrict__ bias, __hip_bfloat16* __restrict__ outv,
    int idx, ProjSmem& sm)
{
  const int b  = idx >> 6;
  const int n0 = (idx & 63) * 64;
  const int tid = threadIdx.x;
  const int o  = tid & 63;
  const int wv = tid >> 6;

  float acc[4][16];
#pragma unroll
  for (int g = 0; g < 4; g++)
#pragma unroll
    for (int k = 0; k < 16; k++) acc[g][k] = 0.f;

  const size_t xb = (size_t)b * 256 * 4096;
  for (int c0 = 0; c0 < 256; c0 += 16) {
#pragma unroll
    for (int i = 0; i < 4; i++) {
      int ii = i * 256 + tid; int cc = ii >> 6, nn = ii & 63;
      sm.v.lx[cc][nn] = X[xb + (size_t)(c0 + cc) * 4096 + n0 + nn];
    }
#pragma unroll
    for (int i = 0; i < 16; i++) {
      int ii = i * 256 + tid; int oo = ii >> 4, cc = ii & 15;
      sm.v.lw[oo][cc] = W[oo * 256 + c0 + cc];
    }
    __syncthreads();
#pragma unroll
    for (int cc = 0; cc < 16; cc++) {
      float w[4] = {sm.v.lw[o][cc], sm.v.lw[o + 64][cc],
                    sm.v.lw[o + 128][cc], sm.v.lw[o + 192][cc]};
      const float4* xp = (const float4*)&sm.v.lx[cc][wv * 16];
#pragma unroll
      for (int k4 = 0; k4 < 4; k4++) {
        float4 xv = xp[k4];
        float xs[4] = {xv.x, xv.y, xv.z, xv.w};
#pragma unroll
        for (int k = 0; k < 4; k++)
#pragma unroll
          for (int g = 0; g < 4; g++)
            acc[g][k4 * 4 + k] += w[g] * xs[k];
      }
    }
    __syncthreads();
  }

#pragma unroll
  for (int g = 0; g < 4; g++) {
    float bb = bias[g * 64 + o];
#pragma unroll
    for (int k = 0; k < 16; k++)
      sm.t[g * 64 + o][wv * 16 + k] = __float2bfloat16(acc[g][k] + bb);
  }
  __syncthreads();
  const int n = tid & 63;
  const int orow = tid >> 6;
#pragma unroll
  for (int j = 0; j < 64; j++) {
    int oo = orow * 64 + j;
    outv[((size_t)(b * 256 + oo)) * 4096 + n0 + n] = sm.t[oo][n];
  }
}

__global__ __launch_bounds__(256) void proj_fused(
    const float* __restrict__ x, const float* __restrict__ z,
    const float* __restrict__ Wq, const float* __restrict__ bq,
    const float* __restrict__ Wk, const float* __restrict__ bk,
    const float* __restrict__ Wv, const float* __restrict__ bv,
    __hip_bfloat16* __restrict__ qp, __hip_bfloat16* __restrict__ kp,
    __hip_bfloat16* __restrict__ vp)
{
  __shared__ ProjSmem sm;
  const int bi = blockIdx.x;
  if (bi < 256)       proj_qk_body(x, Wq, bq, qp, LOG2E, bi, sm);
  else if (bi < 512)  proj_qk_body(z, Wk, bk, kp, 1.0f, bi - 256, sm);
  else                proj_v_body (z, Wv, bv, vp, bi - 512, sm);
}

// ---------------------------------------------------------------------------
// Flash attention, barrier-free main loop.
// Block: (batch b, 32 queries). Wave wv: private keys [wv*1024, wv*1024+1024).
// ---------------------------------------------------------------------------
struct AttnSmem {
  float ostage[256][33];   // [ch][q] fp32 merge/transpose, pad 33
  float redu[4][32];       // iter-0 anchor exchange; reused for l partials
};

union U4 { unsigned u[4]; bf16x8 v; };

__global__ __launch_bounds__(256, 2) void attn_kernel(
    const __hip_bfloat16* __restrict__ qv, const __hip_bfloat16* __restrict__ kv,
    const __hip_bfloat16* __restrict__ vv,
    const float* __restrict__ x_main, const float* __restrict__ gammap,
    float* __restrict__ out)
{
  __shared__ AttnSmem sm;
  const int i  = blockIdx.x;
  // XCD-stable: blockIdx%8 -> XCD; pin each XCD-pair to one batch so that
  // batch's K+V (~3MB) stays L2-resident.
  const int b  = (i & 7) >> 1;
  const int nt = ((i >> 3) << 1) | (i & 1);
  const int n0 = nt * 32;
  const int tid  = threadIdx.x;
  const int wv   = tid >> 6, lane = tid & 63, l32 = lane & 31, half = lane >> 5;
  const int kb   = wv * 1024;   // this wave's private key range

  // Q A/B-fragments: lane holds q[n0+l32][half*8 + cs*16 + j]
  bf16x8 qf[8];
  {
    const __hip_bfloat16* qb = qv + ((size_t)(b * 4096 + n0 + l32)) * 128 + half * 8;
#pragma unroll
    for (int cs = 0; cs < 8; cs++) qf[cs] = *(const bf16x8*)(qb + cs * 16);
  }

  const __hip_bfloat16* khb = kv + ((size_t)(b * 4096 + kb + l32)) * 128 + half * 8;
  const __hip_bfloat16* vb  = vv + ((size_t)(b * 256 + l32)) * 4096 + kb + half * 8;

  f32x16 Oacc[8];
#pragma unroll
  for (int t = 0; t < 8; t++)
#pragma unroll
    for (int r = 0; r < 16; r++) Oacc[t][r] = 0.f;

  float m0 = 0.f;
  float l_lane = 0.f;

  // S^T tile for 32 keys: A=K, B=Q -> D[key-row][query-col].
  auto qk_tile = [&](int it) -> f32x16 {
    f32x16 S;
#pragma unroll
    for (int r = 0; r < 16; r++) S[r] = 0.f;
    const __hip_bfloat16* kp = khb + (size_t)it * (32 * 128);
#pragma unroll
    for (int cs = 0; cs < 8; cs++) {
      bf16x8 kf = *(const bf16x8*)(kp + cs * 16);
      S = __builtin_amdgcn_mfma_f32_32x32x16_bf16(kf, qf[cs], S, 0, 0, 0);
    }
    return S;
  };

  // P = exp2(S - m0); assemble A-layout P frags in-register; PV MFMAs.
  auto pv_tile = [&](int it, const f32x16& S) {
    unsigned p2[8];
    float lsub = 0.f;
#pragma unroll
    for (int t = 0; t < 8; t++) {
      float a = exp2f(S[2 * t]     - m0);
      float c = exp2f(S[2 * t + 1] - m0);
      lsub += a + c;
      union { __hip_bfloat162 h; unsigned u; } cv;
      cv.h = __float22bfloat162_rn(float2{a, c});
      p2[t] = cv.u;
    }
    l_lane += lsub;
    unsigned r2[8];
#pragma unroll
    for (int t = 0; t < 8; t++) r2[t] = (unsigned)__shfl_xor((int)p2[t], 32);
    // reg r of lane(l32,h) = P[key=(r&3)+8*(r>>2)+4h][q=l32]; A-frag needs
    // P[q=l32][key=ks*16+h*8+j]:
    //   h=0: frag[ks] = {p2[ks*4],p2[ks*4+1],r2[ks*4],r2[ks*4+1]}
    //   h=1: frag[ks] = {r2[ks*4+2],r2[ks*4+3],p2[ks*4+2],p2[ks*4+3]}
    U4 f0, f1;
    if (half == 0) {
      f0.u[0] = p2[0]; f0.u[1] = p2[1]; f0.u[2] = r2[0]; f0.u[3] = r2[1];
      f1.u[0] = p2[4]; f1.u[1] = p2[5]; f1.u[2] = r2[4]; f1.u[3] = r2[5];
    } else {
      f0.u[0] = r2[2]; f0.u[1] = r2[3]; f0.u[2] = p2[2]; f0.u[3] = p2[3];
      f1.u[0] = r2[6]; f1.u[1] = r2[7]; f1.u[2] = p2[6]; f1.u[3] = p2[7];
    }
    const bf16x8 pf0 = f0.v, pf1 = f1.v;
    const __hip_bfloat16* vp0 = vb + it * 32;
#pragma unroll
    for (int cht = 0; cht < 8; cht++) {
      const __hip_bfloat16* vc = vp0 + (size_t)cht * (32 * 4096);
      bf16x8 v0 = *(const bf16x8*)(vc);
      Oacc[cht] = __builtin_amdgcn_mfma_f32_32x32x16_bf16(pf0, v0, Oacc[cht], 0, 0, 0);
      bf16x8 v1 = *(const bf16x8*)(vc + 16);
      Oacc[cht] = __builtin_amdgcn_mfma_f32_32x32x16_bf16(pf1, v1, Oacc[cht], 0, 0, 0);
    }
  };

  // ---- iter 0 (peeled): compute anchor m0 = max over first 128 keys ----
  {
    f32x16 S = qk_tile(0);
    float mh = S[0];
#pragma unroll
    for (int r = 1; r < 16; r++) mh = fmaxf(mh, S[r]);
    mh = fmaxf(mh, __shfl_xor(mh, 32));
    if (lane < 32) sm.redu[wv][l32] = mh;
    __syncthreads();
    m0 = fmaxf(fmaxf(sm.redu[0][l32], sm.redu[1][l32]),
               fmaxf(sm.redu[2][l32], sm.redu[3][l32]));
    pv_tile(0, S);
  }

  // ---- barrier-free main loop ----
#pragma unroll 1
  for (int it = 1; it < 32; ++it) {
    f32x16 S = qk_tile(it);
    pv_tile(it, S);
  }

  // ---- epilogue: merge 4 waves' O via rotated-quarter LDS accumulation ----
  __syncthreads();    // everyone done with main loop (and iter-0 redu reads)
  float lfull = l_lane + __shfl_xor(l_lane, 32);
  if (lane < 32) sm.redu[wv][l32] = lfull;
#pragma unroll
  for (int p = 0; p < 4; ++p) {
    const int qt = (wv + p) & 3;    // channel quarter for this wave this phase
#pragma unroll
    for (int cq = 0; cq < 2; ++cq) {
      const int cht = qt * 2 + cq;
#pragma unroll
      for (int r = 0; r < 16; ++r) {
        const int row = (r & 3) + 8 * (r >> 2) + 4 * half;
        if (p == 0) sm.ostage[cht * 32 + l32][row]  = Oacc[cht][r];
        else        sm.ostage[cht * 32 + l32][row] += Oacc[cht][r];
      }
    }
    __syncthreads();
  }

  const float gmm = gammap[0];
  const int nr = tid & 31;
  const int og = tid >> 5;
  const float ltot = sm.redu[0][nr] + sm.redu[1][nr] + sm.redu[2][nr] + sm.redu[3][nr];
  const float rinv = 1.0f / ltot;
#pragma unroll
  for (int j = 0; j < 32; ++j) {
    int oo = og * 32 + j;
    size_t g = ((size_t)(b * 256 + oo)) * 4096 + n0 + nr;
    out[g] = gmm * sm.ostage[oo][nr] * rinv + x_main[g];
  }
}

// ---------------------------------------------------------------------------
extern "C" void kernel_launch(void* const* d_in, const int* in_sizes, int n_in,
                              void* d_out, int out_size, void* d_ws, size_t ws_size,
                              hipStream_t stream) {
  (void)in_sizes; (void)n_in; (void)out_size; (void)ws_size;
  const float* x  = (const float*)d_in[0];
  const float* z  = (const float*)d_in[1];
  const float* Wq = (const float*)d_in[2];
  const float* bq = (const float*)d_in[3];
  const float* Wk = (const float*)d_in[4];
  const float* bk = (const float*)d_in[5];
  const float* Wv = (const float*)d_in[6];
  const float* bv = (const float*)d_in[7];
  const float* gm = (const float*)d_in[8];
  float* out = (float*)d_out;

  char* ws = (char*)d_ws;
  const size_t QSZ = (size_t)4 * 4096 * 128 * sizeof(__hip_bfloat16);  // 4 MiB
  __hip_bfloat16* qp = (__hip_bfloat16*)(ws);
  __hip_bfloat16* kp = (__hip_bfloat16*)(ws + QSZ);
  __hip_bfloat16* vp = (__hip_bfloat16*)(ws + 2 * QSZ);                // 8 MiB

  proj_fused<<<768, 256, 0, stream>>>(x, z, Wq, bq, Wk, bk, Wv, bv, qp, kp, vp);
  attn_kernel<<<512, 256, 0, stream>>>(qp, kp, vp, x, gm, out);
}